// Round 10
// baseline (181.102 us; speedup 1.0000x reference)
//
#include <hip/hip_runtime.h>
#include <hip/hip_bf16.h>
#include <stdint.h>

typedef __bf16 bf16;
typedef __attribute__((ext_vector_type(8))) __bf16 bf16x8;
typedef __attribute__((ext_vector_type(4))) __bf16 bf16x4;
typedef __attribute__((ext_vector_type(4))) float f32x4;

#define AS1 __attribute__((address_space(1)))
#define AS3 __attribute__((address_space(3)))

__device__ __forceinline__ void async16(const void* g, void* l) {
  __builtin_amdgcn_global_load_lds((AS1 uint32_t*)(g), (AS3 uint32_t*)(l), 16, 0, 0);
}

__device__ __forceinline__ f32x4 mfma_bf16(bf16x8 a, bf16x8 b, f32x4 c) {
  return __builtin_amdgcn_mfma_f32_16x16x32_bf16(a, b, c, 0, 0, 0);
}

__device__ __forceinline__ uint32_t pack2_bf16(float a, float b) {
  union { __hip_bfloat162 h2; uint32_t u; } u;
  u.h2 = __float22bfloat162_rn(float2{a, b});
  return u.u;
}

// ---------------------------------------------------------------- fused casts
__global__ __launch_bounds__(256) void cast_all_kernel(
    const float* __restrict__ x, const float* __restrict__ w1,
    const float* __restrict__ w2, bf16* __restrict__ xb,
    bf16* __restrict__ w1b, bf16* __restrict__ w2b) {
  const int bid = blockIdx.x;
  const float* src;
  bf16* dst;
  int base;
  if (bid < 4096) { src = x;  dst = xb;  base = bid; }
  else if (bid < 7168) { src = w1; dst = w1b; base = bid - 4096; }
  else { src = w2; dst = w2b; base = bid - 7168; }
  const int i = (base * 256 + threadIdx.x) * 4;
  const float4 v = *(const float4*)(src + i);
  bf16x4 o;
  o[0] = (bf16)v.x; o[1] = (bf16)v.y; o[2] = (bf16)v.z; o[3] = (bf16)v.w;
  *(bf16x4*)(dst + i) = o;
}

// ---------------------------------------------------------------- GEMM1: qkv = x @ qkv_w^T
// Epilogue: Q -> row-major QB[4096][1024]; K -> KFRAG; V -> VFRAG.
// KFRAG[bh][t][m][kk][lane][8] = K[t*64 + sigma(m,col)][kk*32 + quad*8 + j]
// VFRAG[bh][t][d][kk][lane][8] = V[t*64 + kk*32 + quad*8 + j][d*16 + col]
// (lane = quad*16 + col) -> attn fragment loads are lane-contiguous 16B chunks.
__global__ __launch_bounds__(256) void gemm_qkv_kernel(
    const bf16* __restrict__ A, const bf16* __restrict__ W,
    bf16* __restrict__ QB, bf16* __restrict__ KF, bf16* __restrict__ VF) {
  constexpr int K = 1024;
  __shared__ __align__(16) bf16 sm[2 * 128 * 32];  // 16 KB; reused as s2[64][128]
  const int tid = threadIdx.x;
  const int w = tid >> 6, lane = tid & 63;
  const int m0 = blockIdx.x * 128, n0 = blockIdx.y * 128;
  const int wm = (w >> 1) * 64, wn = (w & 1) * 64;
  const int lrow = lane & 15, quad = lane >> 4;
  const int lk = quad * 8;
  f32x4 acc[4][4] = {};

  for (int k0 = 0; k0 < K; k0 += 32) {
#pragma unroll
    for (int i = 0; i < 4; ++i) {
      const int c = tid + 256 * i;
      const bf16* src = (c < 512)
          ? (A + (size_t)(m0 + (c >> 2)) * K + k0 + (c & 3) * 8)
          : (W + (size_t)(n0 + ((c - 512) >> 2)) * K + k0 + (c & 3) * 8);
      async16(src, sm + (w * 64 + i * 256) * 8);
    }
    __syncthreads();
    bf16x8 af[4], bfr[4];
#pragma unroll
    for (int mi = 0; mi < 4; ++mi)
      af[mi] = *(const bf16x8*)&sm[(wm + mi * 16 + lrow) * 32 + lk];
#pragma unroll
    for (int ni = 0; ni < 4; ++ni)
      bfr[ni] = *(const bf16x8*)&sm[128 * 32 + (wn + ni * 16 + lrow) * 32 + lk];
#pragma unroll
    for (int mi = 0; mi < 4; ++mi)
#pragma unroll
      for (int ni = 0; ni < 4; ++ni)
        acc[mi][ni] = mfma_bf16(af[mi], bfr[ni], acc[mi][ni]);
    __syncthreads();
  }

  bf16* s2 = sm;  // [64][128]
  const int bb = m0 >> 11;           // batch
  const int tb = (m0 & 2047) >> 6;   // kv-tile base within batch
  if (n0 < 1024) {
    // ---- Q: row-major QB[m][n], LDS transpose by m-halves, 16B stores
#pragma unroll
    for (int c = 0; c < 2; ++c) {
      if ((w >> 1) == c) {
#pragma unroll
        for (int mi = 0; mi < 4; ++mi)
#pragma unroll
          for (int ni = 0; ni < 4; ++ni) {
            const int nr = wn + ni * 16 + lrow;
#pragma unroll
            for (int r = 0; r < 4; ++r)
              s2[(mi * 16 + quad * 4 + r) * 128 + nr] = (bf16)acc[mi][ni][r];
          }
      }
      __syncthreads();
#pragma unroll
      for (int p = 0; p < 4; ++p) {
        const int row = p * 16 + (tid >> 4);
        const int colc = (tid & 15) * 8;
        const bf16x8 v = *(const bf16x8*)&s2[row * 128 + colc];
        *(bf16x8*)(QB + (size_t)(m0 + c * 64 + row) * 1024 + n0 + colc) = v;
      }
      __syncthreads();
    }
  } else if (n0 < 2048) {
    // ---- K: same m-half LDS transpose, then fragment-format stores
    const int hh0 = (n0 - 1024) >> 6;
#pragma unroll
    for (int c = 0; c < 2; ++c) {
      if ((w >> 1) == c) {
#pragma unroll
        for (int mi = 0; mi < 4; ++mi)
#pragma unroll
          for (int ni = 0; ni < 4; ++ni) {
            const int nr = wn + ni * 16 + lrow;
#pragma unroll
            for (int r = 0; r < 4; ++r)
              s2[(mi * 16 + quad * 4 + r) * 128 + nr] = (bf16)acc[mi][ni][r];
          }
      }
      __syncthreads();
#pragma unroll
      for (int i = 0; i < 4; ++i) {
        const int L = tid + 256 * i;   // 1024 chunks: 2 heads x 4 m x 2 kk x 64 lanes
        const int lane_l = L & 63, rest = L >> 6;
        const int kk = rest & 1, m = (rest >> 1) & 3, hh = rest >> 3;
        const int col_l = lane_l & 15, quad_l = lane_l >> 4;
        const int sigma = 32 * (m & 1) + (col_l >> 2) * 8 + 4 * (m >> 1) + (col_l & 3);
        const bf16x8 v = *(const bf16x8*)&s2[sigma * 128 + hh * 64 + kk * 32 + quad_l * 8];
        const int bh = bb * 16 + hh0 + hh;
        *(bf16x8*)(KF + (((size_t)(bh * 32 + tb + c) * 512 + (m * 2 + kk) * 64 + lane_l) << 3)) = v;
      }
      __syncthreads();
    }
  } else {
    // ---- V: n-half LDS transpose (s2[d_loc][t]), then fragment-format stores
    const int hv0 = (n0 - 2048) >> 6;
#pragma unroll
    for (int c = 0; c < 2; ++c) {
      if ((w & 1) == c) {
#pragma unroll
        for (int mi = 0; mi < 4; ++mi)
#pragma unroll
          for (int ni = 0; ni < 4; ++ni) {
            const int nl = ni * 16 + lrow;
            bf16x4 pk4;
#pragma unroll
            for (int r = 0; r < 4; ++r) pk4[r] = (bf16)acc[mi][ni][r];
            *(bf16x4*)&s2[nl * 128 + wm + mi * 16 + quad * 4] = pk4;
          }
      }
      __syncthreads();
#pragma unroll
      for (int i = 0; i < 4; ++i) {
        const int L = tid + 256 * i;   // 1024 chunks: 2 tiles x 4 d x 2 kk x 64 lanes
        const int lane_l = L & 63, rest = L >> 6;
        const int kk = rest & 1, d = (rest >> 1) & 3, Tt = rest >> 3;
        const bf16x8 v = *(const bf16x8*)&s2[(d * 16 + (lane_l & 15)) * 128 +
                                             Tt * 64 + kk * 32 + (lane_l >> 4) * 8];
        const int bh = bb * 16 + hv0 + c;
        *(bf16x8*)(VF + (((size_t)(bh * 32 + tb + Tt) * 512 + (d * 2 + kk) * 64 + lane_l) << 3)) = v;
      }
      __syncthreads();
    }
  }
}

// ---------------------------------------------------------------- attention (flash, causal)
// ZERO-LDS, ZERO-BARRIER: per wave 32 q-rows, K/V fragments loaded from
// pre-formatted KFRAG/VFRAG (lane-contiguous 16B -> 4 coalesced requests/instr,
// L2-resident). Register prefetch: kf(t+1) after QK(t); vf(t+1) after PV(t).
// Unnormalized softmax p = exp2(st); l via ones-MFMA. sigma C-layout == PV B-frag.
template <bool HALF, bool MASK, bool PRE>
__device__ __forceinline__ void attn_body(
    bf16x8 (&kf)[4][2], bf16x8 (&vf)[4][2],
    const bf16* KFn, const bf16* VFn, int lane,
    const bf16x8 (&qf)[2][2], f32x4 (&accO)[4][2], f32x4 (&accL)[2],
    bf16x8 onesv, int col, int quad) {
  const float NEG_INF = -__builtin_inff();

  // S^T = K . Q^T
  f32x4 st[2][4];
#pragma unroll
  for (int qtile = 0; qtile < 2; ++qtile)
#pragma unroll
    for (int m = 0; m < 4; ++m) st[qtile][m] = f32x4{0.f, 0.f, 0.f, 0.f};
#pragma unroll
  for (int kk = 0; kk < 2; ++kk)
#pragma unroll
    for (int m = 0; m < 4; ++m) {
      if (HALF && (m & 1)) continue;
#pragma unroll
      for (int qtile = 0; qtile < 2; ++qtile)
        st[qtile][m] = mfma_bf16(kf[m][kk], qf[qtile][kk], st[qtile][m]);
    }

  // prefetch next K fragments (WAR on kf keeps this after the QK MFMAs)
  if (PRE) {
#pragma unroll
    for (int m = 0; m < 4; ++m)
#pragma unroll
      for (int kk = 0; kk < 2; ++kk)
        kf[m][kk] = *(const bf16x8*)(KFn + (((m * 2 + kk) * 64 + lane) << 3));
  }

  if (MASK) {
#pragma unroll
    for (int qtile = 0; qtile < 2; ++qtile) {
      const int rq = qtile * 16 + col;  // +32 on both sides cancels for odd qt
#pragma unroll
      for (int m = 0; m < 4; ++m) {
        if (HALF ? ((m & 1) != 0) : ((m & 1) == 0)) continue;
        const int kvb = quad * 8 + 4 * (m >> 1);
#pragma unroll
        for (int r = 0; r < 4; ++r)
          st[qtile][m][r] = (kvb + r <= rq) ? st[qtile][m][r] : NEG_INF;
      }
    }
  }

  // p = exp2(st), packed bf16
  uint32_t pk[2][4][2];
#pragma unroll
  for (int qtile = 0; qtile < 2; ++qtile)
#pragma unroll
    for (int m = 0; m < 4; ++m) {
      if (HALF && (m & 1)) continue;
      const float p0 = __builtin_amdgcn_exp2f(st[qtile][m][0]);
      const float p1 = __builtin_amdgcn_exp2f(st[qtile][m][1]);
      const float p2 = __builtin_amdgcn_exp2f(st[qtile][m][2]);
      const float p3 = __builtin_amdgcn_exp2f(st[qtile][m][3]);
      pk[qtile][m][0] = pack2_bf16(p0, p1);
      pk[qtile][m][1] = pack2_bf16(p2, p3);
    }

  // O^T += V^T . P^T ; l += ones . P^T
#pragma unroll
  for (int kk = 0; kk < (HALF ? 1 : 2); ++kk)
#pragma unroll
    for (int qtile = 0; qtile < 2; ++qtile) {
      union { uint32_t u[4]; bf16x8 v; } f;
      f.u[0] = pk[qtile][kk][0];
      f.u[1] = pk[qtile][kk][1];
      f.u[2] = pk[qtile][2 + kk][0];
      f.u[3] = pk[qtile][2 + kk][1];
      accL[qtile] = mfma_bf16(onesv, f.v, accL[qtile]);
#pragma unroll
      for (int d = 0; d < 4; ++d)
        accO[d][qtile] = mfma_bf16(vf[d][kk], f.v, accO[d][qtile]);
    }

  // prefetch next V fragments
  if (PRE) {
#pragma unroll
    for (int d = 0; d < 4; ++d)
#pragma unroll
      for (int kk = 0; kk < 2; ++kk)
        vf[d][kk] = *(const bf16x8*)(VFn + (((d * 2 + kk) * 64 + lane) << 3));
  }
}

__global__ __launch_bounds__(256) void attn_kernel(
    const bf16* __restrict__ QB, const bf16* __restrict__ KF,
    const bf16* __restrict__ VF, bf16* __restrict__ AO) {
  const int bh = blockIdx.x;
  const int b = bh >> 4, h = bh & 15;
  const int tid = threadIdx.x, w = tid >> 6, lane = tid & 63;
  const int qt = 4 * (15 - (int)blockIdx.y) + w;  // 0..63, heavy blocks first
  const int q0 = qt * 32;
  const int col = lane & 15, quad = lane >> 4;
  const bf16* Qb = QB + (size_t)b * 2048 * 1024 + h * 64;
  const bf16* KFb = KF + ((size_t)bh * 32) * 4096;
  const bf16* VFb = VF + ((size_t)bh * 32) * 4096;
  constexpr float QSCALE = 0.18033688011112042f;  // 0.125 * log2(e)

  union { uint32_t u[4]; bf16x8 v; } ones;
  ones.u[0] = 0x3F803F80u; ones.u[1] = 0x3F803F80u;
  ones.u[2] = 0x3F803F80u; ones.u[3] = 0x3F803F80u;

  // Q B-frags, pre-scaled into log2 domain
  int qrow[2];
  bf16x8 qf[2][2];
#pragma unroll
  for (int qtile = 0; qtile < 2; ++qtile) {
    qrow[qtile] = q0 + qtile * 16 + col;
#pragma unroll
    for (int kk = 0; kk < 2; ++kk) {
      bf16x8 v = *(const bf16x8*)(Qb + (size_t)qrow[qtile] * 1024 + kk * 32 + quad * 8);
#pragma unroll
      for (int e = 0; e < 8; ++e) v[e] = (bf16)((float)v[e] * QSCALE);
      qf[qtile][kk] = v;
    }
  }

  // prologue: tile-0 fragments
  bf16x8 kf[4][2], vf[4][2];
#pragma unroll
  for (int m = 0; m < 4; ++m)
#pragma unroll
    for (int kk = 0; kk < 2; ++kk)
      kf[m][kk] = *(const bf16x8*)(KFb + (((m * 2 + kk) * 64 + lane) << 3));
#pragma unroll
  for (int d = 0; d < 4; ++d)
#pragma unroll
    for (int kk = 0; kk < 2; ++kk)
      vf[d][kk] = *(const bf16x8*)(VFb + (((d * 2 + kk) * 64 + lane) << 3));

  f32x4 accO[4][2] = {};
  f32x4 accL[2] = {};

  const int tL = qt >> 1;
  const bf16* Kt = KFb;
  const bf16* Vt = VFb;
#pragma unroll 1
  for (int t = 0; t < tL; ++t) {
    attn_body<false, false, true>(kf, vf, Kt + 4096, Vt + 4096, lane, qf, accO,
                                  accL, ones.v, col, quad);
    Kt += 4096;
    Vt += 4096;
  }
  if (qt & 1)
    attn_body<false, true, false>(kf, vf, nullptr, nullptr, lane, qf, accO,
                                  accL, ones.v, col, quad);
  else
    attn_body<true, true, false>(kf, vf, nullptr, nullptr, lane, qf, accO,
                                 accL, ones.v, col, quad);

  // epilogue: per-lane l from ones-MFMA; normalize; 8B packed stores
  bf16* Ob = AO + (size_t)b * 2048 * 1024 + h * 64;
#pragma unroll
  for (int qtile = 0; qtile < 2; ++qtile) {
    const float inv = 1.0f / accL[qtile][0];
#pragma unroll
    for (int d = 0; d < 4; ++d) {
      bf16x4 o;
#pragma unroll
      for (int r = 0; r < 4; ++r) o[r] = (bf16)(accO[d][qtile][r] * inv);
      *(bf16x4*)(Ob + (size_t)qrow[qtile] * 1024 + d * 16 + quad * 4) = o;
    }
  }
}

// ---------------------------------------------------------------- GEMM2: y = attn_out @ out_w^T
__global__ __launch_bounds__(256) void gemm_out_kernel(
    const bf16* __restrict__ A, const bf16* __restrict__ W,
    float* __restrict__ C) {
  constexpr int K = 1024;
  __shared__ __align__(16) bf16 sm[2 * 128 * 32];
  const int tid = threadIdx.x;
  const int w = tid >> 6, lane = tid & 63;
  const int m0 = blockIdx.x * 128, n0 = blockIdx.y * 128;
  const int wm = (w >> 1) * 64, wn = (w & 1) * 64;
  const int lrow = lane & 15, lk = (lane >> 4) * 8;
  f32x4 acc[4][4] = {};

  for (int k0 = 0; k0 < K; k0 += 32) {
#pragma unroll
    for (int i = 0; i < 4; ++i) {
      const int c = tid + 256 * i;
      const bf16* src = (c < 512)
          ? (A + (size_t)(m0 + (c >> 2)) * K + k0 + (c & 3) * 8)
          : (W + (size_t)(n0 + ((c - 512) >> 2)) * K + k0 + (c & 3) * 8);
      async16(src, sm + (w * 64 + i * 256) * 8);
    }
    __syncthreads();
    bf16x8 af[4], bfr[4];
#pragma unroll
    for (int mi = 0; mi < 4; ++mi)
      af[mi] = *(const bf16x8*)&sm[(wm + mi * 16 + lrow) * 32 + lk];
#pragma unroll
    for (int ni = 0; ni < 4; ++ni)
      bfr[ni] = *(const bf16x8*)&sm[128 * 32 + (wn + ni * 16 + lrow) * 32 + lk];
#pragma unroll
    for (int mi = 0; mi < 4; ++mi)
#pragma unroll
      for (int ni = 0; ni < 4; ++ni)
        acc[mi][ni] = mfma_bf16(af[mi], bfr[ni], acc[mi][ni]);
    __syncthreads();
  }

#pragma unroll
  for (int mi = 0; mi < 4; ++mi)
#pragma unroll
    for (int ni = 0; ni < 4; ++ni) {
      const int n = n0 + wn + ni * 16 + lrow;
#pragma unroll
      for (int r = 0; r < 4; ++r) {
        const int m = m0 + wm + mi * 16 + (lane >> 4) * 4 + r;
        C[(size_t)m * 1024 + n] = acc[mi][ni][r];
      }
    }
}

// ---------------------------------------------------------------- launch
extern "C" void kernel_launch(void* const* d_in, const int* in_sizes, int n_in,
                              void* d_out, int out_size, void* d_ws, size_t ws_size,
                              hipStream_t stream) {
  const float* x     = (const float*)d_in[0];
  const float* qkv_w = (const float*)d_in[1];
  const float* out_w = (const float*)d_in[2];
  float* out = (float*)d_out;

  char* ws = (char*)d_ws;
  bf16* xb    = (bf16*)(ws);                      // 8 MB  [4096][1024]
  bf16* aob   = (bf16*)(ws);                      // 8 MB  alias (xb dead after gemm_qkv)
  bf16* wqkvb = (bf16*)(ws + 8u * 1024 * 1024);   // 6 MB  [3072][1024]
  bf16* wob   = (bf16*)(ws + 14u * 1024 * 1024);  // 2 MB  [1024][1024]
  bf16* qb    = (bf16*)(ws + 16u * 1024 * 1024);  // 8 MB  Q rows [4096][1024]
  bf16* kfrag = (bf16*)(ws + 24u * 1024 * 1024);  // 8 MB  KFRAG [32][32][4096]
  bf16* vfrag = (bf16*)(ws + 32u * 1024 * 1024);  // 8 MB  VFRAG [32][32][4096]

  cast_all_kernel<<<8192, 256, 0, stream>>>(x, qkv_w, out_w, xb, wqkvb, wob);
  gemm_qkv_kernel<<<dim3(32, 24), 256, 0, stream>>>(xb, wqkvb, qb, kfrag, vfrag);
  attn_kernel<<<dim3(32, 16), 256, 0, stream>>>(qb, kfrag, vfrag, aob);
  gemm_out_kernel<<<dim3(32, 8), 256, 0, stream>>>(aob, wob, out);
}